// Round 19
// baseline (691.519 us; speedup 1.0000x reference)
//
#include <hip/hip_runtime.h>

// R19 (= R18 fixed): outlier append-list. A never touches `out` (outlier
// corners -> (idx,val) records in ws; ~1M expected). B plain-stores out =
// gather of covering tile cells (NO memset of out, NO out-read). C applies
// records with atomics after B. Removes 28MB memset-write + 28MB out-read.
// Reference semantics (exact):
//   locs = max(grid + flow, 0)
//   delta = locs - floor(locs)           (from UNclamped floor)
//   base  = min((int)floor(locs), dim-1)
//   corner per axis = min(base + {0,1}, dim-1)   (collapsed corners add twice)

typedef unsigned long long u64;

constexpr int H = 192, W = 192, Dd = 192;
constexpr int N = H * W * Dd;
constexpr int WD = W * Dd;

constexpr int BI = 8, BJ = 8, BK = 32;
constexpr int HL = 2;
constexpr int TI = BI + 2 * HL;              // 12
constexpr int TJ = BJ + 2 * HL;              // 12
constexpr int TK = BK + 2 * HL;              // 36 (div by 4 -> aligned quads)
constexpr int TJS = TJ - 1;                  // 11
constexpr int TKS = TK - 1;                  // 35
constexpr int TBINS = TI * TJS * TKS;        // 4620 u64 = 36.96 KB
constexpr int TCELLS = TI * TJ * TK;         // 5184 cells per tile
constexpr int NBI = H / BI, NBJ = W / BJ, NBK = Dd / BK;   // 24,24,6
constexpr int NBLK = NBI * NBJ * NBK;        // 3456

// ws layout: [i16 tiles][16B-aligned counter][records (u64 each)]
constexpr size_t TILE_BYTES = (size_t)NBLK * TCELLS * sizeof(short);   // 35.83 MB
constexpr size_t CNT_OFF    = (TILE_BYTES + 15) & ~(size_t)15;
constexpr size_t REC_OFF    = CNT_OFF + 16;
constexpr unsigned REC_MIN  = 2u * 1024 * 1024;   // require >= 2M record slots

constexpr float SCALE      = 512.0f;         // bin scale 2^9
constexpr float INV_SCALE2 = 1.0f / 256.0f;  // ws scale 2^8

__device__ __forceinline__ u64 pack4(float fa, float fb, float fc, float fd) {
    const int d0 = (int)rintf(fa * SCALE);
    const int d1 = (int)rintf(fb * SCALE);
    const int d2 = (int)rintf(fc * SCALE);
    const int d3 = (int)rintf(fd * SCALE);
    const int lo = d0 + (d1 << 16);
    const int hi = d2 + (d3 << 16) - (lo < 0 ? 1 : 0);
    return ((u64)(unsigned)hi << 32) | (unsigned)lo;
}

__device__ __forceinline__ u64 pack_rec(int idx, float v) {
    return ((u64)__float_as_uint(v) << 32) | (unsigned)idx;
}

// ---- Kernel A: scatter -> bins; outliers -> record list; tile -> i16 ws ----
__global__ __launch_bounds__(512, 8) void splat_tile_kernel(const float* __restrict__ src,
                                                            const float* __restrict__ flow,
                                                            short* __restrict__ wst,
                                                            u64* __restrict__ rec,
                                                            unsigned* __restrict__ rec_cnt,
                                                            unsigned rec_cap) {
    __shared__ __align__(16) u64 bins[TBINS];

    const int t  = threadIdx.x;
    const int bk = blockIdx.x, bj = blockIdx.y, bi = blockIdx.z;
    const int i0 = bi * BI, j0 = bj * BJ, k0 = bk * BK;
    const int xg0 = i0 - HL, yg0 = j0 - HL, zg0 = k0 - HL;

    {
        const float4 z4 = make_float4(0.f, 0.f, 0.f, 0.f);
        float4* b4 = reinterpret_cast<float4*>(bins);
        for (int c = t; c < TBINS * 2 / 4; c += 512) b4[c] = z4;
    }
    __syncthreads();

    // --- scatter: 2048 voxels, 4 consecutive-z per thread ---
    {
        const int kg = (t & 7) * 4;
        const int cj = (t >> 3) & 7;
        const int ci = t >> 6;
        const int i = i0 + ci, j = j0 + cj, k = k0 + kg;
        const int off = i * WD + j * Dd + k;

        const float4 s4  = *reinterpret_cast<const float4*>(src + off);
        const float4 fx4 = *reinterpret_cast<const float4*>(flow + off);
        const float4 fy4 = *reinterpret_cast<const float4*>(flow + N + off);
        const float4 fz4 = *reinterpret_cast<const float4*>(flow + 2 * N + off);

        const float sa[4]  = {s4.x, s4.y, s4.z, s4.w};
        const float fxa[4] = {fx4.x, fx4.y, fx4.z, fx4.w};
        const float fya[4] = {fy4.x, fy4.y, fy4.z, fy4.w};
        const float fza[4] = {fz4.x, fz4.y, fz4.z, fz4.w};

#pragma unroll
        for (int q = 0; q < 4; ++q) {
            const float lx = fmaxf((float)i       + fxa[q], 0.0f);
            const float ly = fmaxf((float)j       + fya[q], 0.0f);
            const float lz = fmaxf((float)(k + q) + fza[q], 0.0f);

            const float bx = floorf(lx), by = floorf(ly), bz = floorf(lz);
            const float dx = lx - bx,    dy = ly - by,    dz = lz - bz;

            const int x0 = min((int)bx, H - 1);
            const int y0 = min((int)by, W - 1);
            const int z0 = min((int)bz, Dd - 1);
            const int x1 = min(x0 + 1, H - 1);
            const int y1 = min(y0 + 1, W - 1);
            const int z1 = min(z0 + 1, Dd - 1);

            const float s = sa[q];
            const float dyf = (y1 > y0) ? dy : 0.0f;   // collapse -> full weight in clamped cell
            const float dzf = (z1 > z0) ? dz : 0.0f;

            const int a0 = x0 - xg0, a1 = x1 - xg0;
            const int b0 = y0 - yg0;
            const int c0 = z0 - zg0;

            const bool fast = ((unsigned)a0 < (unsigned)TI) & ((unsigned)a1 < (unsigned)TI) &
                              ((unsigned)b0 < (unsigned)TJS) &
                              ((unsigned)c0 < (unsigned)TKS);

            if (__builtin_expect(fast, 1)) {
                const float w0 = s * (1.0f - dx);
                const float w1 = s * dx;
                {
                    const float m1 = w0 * dyf, m2 = w0 * dzf;
                    const float FD = m1 * dzf;
                    const float FB = m1 - FD, FC = m2 - FD;
                    const float FA = (w0 - m1) - FC;
                    atomicAdd(&bins[(a0 * TJS + b0) * TKS + c0], pack4(FA, FB, FC, FD));
                }
                {
                    const float m1 = w1 * dyf, m2 = w1 * dzf;
                    const float FD = m1 * dzf;
                    const float FB = m1 - FD, FC = m2 - FD;
                    const float FA = (w1 - m1) - FC;
                    atomicAdd(&bins[(a1 * TJS + b0) * TKS + c0], pack4(FA, FB, FC, FD));
                }
            } else {
                // outlier: append 8 corner records (applied by kernel C)
                const float wx0 = 1.0f - dx, wy0 = 1.0f - dy, wz0 = 1.0f - dz;
                const float a00 = s * wx0 * wy0;
                const float a01 = s * wx0 * dy;
                const float a10 = s * dx * wy0;
                const float a11 = s * dx * dy;
                const unsigned base = atomicAdd(rec_cnt, 8u);  // wave-aggregated (m20)
                if (base + 8u <= rec_cap) {
                    u64* r = rec + base;
                    r[0] = pack_rec(x0 * WD + y0 * Dd + z0, a00 * wz0);
                    r[1] = pack_rec(x0 * WD + y0 * Dd + z1, a00 * dz);
                    r[2] = pack_rec(x0 * WD + y1 * Dd + z0, a01 * wz0);
                    r[3] = pack_rec(x0 * WD + y1 * Dd + z1, a01 * dz);
                    r[4] = pack_rec(x1 * WD + y0 * Dd + z0, a10 * wz0);
                    r[5] = pack_rec(x1 * WD + y0 * Dd + z1, a10 * dz);
                    r[6] = pack_rec(x1 * WD + y1 * Dd + z0, a11 * wz0);
                    r[7] = pack_rec(x1 * WD + y1 * Dd + z1, a11 * dz);
                }
            }
        }
    }
    __syncthreads();

    // --- quad-decode epilogue: 4 z-cells -> one short4 ws store (scale 2^8) ---
    short* wt = wst + (size_t)((bi * NBJ + bj) * NBK + bk) * TCELLS;
    for (int qd = t; qd < TCELLS / 4; qd += 512) {
        const int c0  = qd * 4;
        const int z0q = c0 % TK;
        const int row = c0 / TK;
        const int b   = row % TJ;
        const int a   = row / TJ;

        const int rb = (a * TJS + b) * TKS;
        const int rm = rb - TKS;
        const bool hb = (b < TJS), hm = (b > 0);

        u64 tb[5], tm[5];
#pragma unroll
        for (int d = 0; d < 5; ++d) {
            const int zi = z0q - 1 + d;
            const bool zok = ((unsigned)zi < (unsigned)TKS);
            tb[d] = (hb && zok) ? bins[rb + zi] : 0ull;
            tm[d] = (hm && zok) ? bins[rm + zi] : 0ull;
        }

        int A0[5], C2[5], B1[5], D3[5];
#pragma unroll
        for (int d = 0; d < 5; ++d) {
            const int lob = (int)(unsigned)tb[d];
            const int hib = (int)(unsigned)(tb[d] >> 32) + (lob < 0 ? 1 : 0);
            A0[d] = (int)(short)(unsigned short)lob;          // F_A
            C2[d] = (int)(short)(unsigned short)hib;          // F_C
            const int lom = (int)(unsigned)tm[d];
            const int him = (int)(unsigned)(tm[d] >> 32) + (lom < 0 ? 1 : 0);
            const int f0m = (int)(short)(unsigned short)lom;
            B1[d] = (lom - f0m) >> 16;                        // F_B
            const int f2m = (int)(short)(unsigned short)him;
            D3[d] = (him - f2m) >> 16;                        // F_D
        }

        short4 sv;
        sv.x = (short)((A0[1] + B1[1] + C2[0] + D3[0] + 1) >> 1);
        sv.y = (short)((A0[2] + B1[2] + C2[1] + D3[1] + 1) >> 1);
        sv.z = (short)((A0[3] + B1[3] + C2[2] + D3[2] + 1) >> 1);
        sv.w = (short)((A0[4] + B1[4] + C2[3] + D3[3] + 1) >> 1);
        *reinterpret_cast<short4*>(wt + c0) = sv;
    }
}

// ---- Kernel B: out = gather of covering tile cells (plain store) ----
__global__ __launch_bounds__(256) void gather_tiles_kernel(const short* __restrict__ ws,
                                                           float* __restrict__ out) {
    const int tid = blockIdx.x * 256 + threadIdx.x;
    const int n0 = tid * 4;
    if (n0 >= N) return;

    const int i   = n0 / WD;
    const int rem = n0 - i * WD;
    const int j   = rem / Dd;
    const int z0  = rem - j * Dd;

    int acc[4] = {0, 0, 0, 0};

    const int biA = (i + HL) >> 3;
    const int bjA = (j + HL) >> 3;

#pragma unroll
    for (int dbi = 0; dbi < 2; ++dbi) {
        const int bi = biA - dbi;
        if ((unsigned)bi >= (unsigned)NBI) continue;
        const int a = i - (bi * BI - HL);
        if ((unsigned)a >= (unsigned)TI) continue;
#pragma unroll
        for (int dbj = 0; dbj < 2; ++dbj) {
            const int bj = bjA - dbj;
            if ((unsigned)bj >= (unsigned)NBJ) continue;
            const int b = j - (bj * BJ - HL);
            if ((unsigned)b >= (unsigned)TJ) continue;

            const short* pbase = ws + (size_t)((bi * NBJ + bj) * NBK) * TCELLS
                               + (a * TJ + b) * TK;
#pragma unroll
            for (int q = 0; q < 4; ++q) {
                const int z = z0 + q;
                const int bkA = (z + HL) >> 5;
#pragma unroll
                for (int dbk = 0; dbk < 2; ++dbk) {
                    const int bk = bkA - dbk;
                    if ((unsigned)bk >= (unsigned)NBK) continue;
                    const int c = z - (bk * BK - HL);
                    if ((unsigned)c >= (unsigned)TK) continue;
                    acc[q] += pbase[(size_t)bk * TCELLS + c];
                }
            }
        }
    }
    float4 r;
    r.x = (float)acc[0] * INV_SCALE2;
    r.y = (float)acc[1] * INV_SCALE2;
    r.z = (float)acc[2] * INV_SCALE2;
    r.w = (float)acc[3] * INV_SCALE2;
    *reinterpret_cast<float4*>(out + n0) = r;
}

// ---- Kernel C: apply outlier records (runs after B) ----
__global__ __launch_bounds__(256) void apply_records_kernel(const u64* __restrict__ rec,
                                                            const unsigned* __restrict__ rec_cnt,
                                                            unsigned rec_cap,
                                                            float* __restrict__ out) {
    const unsigned n = min(*rec_cnt, rec_cap);
    const unsigned stride = gridDim.x * 256;
    for (unsigned idx = blockIdx.x * 256 + threadIdx.x; idx < n; idx += stride) {
        const u64 r = rec[idx];
        unsafeAtomicAdd(out + (unsigned)(r & 0xffffffffu), __uint_as_float((unsigned)(r >> 32)));
    }
}

// ---- fallback: single kernel with atomic flush (requires memset of out) ----
__global__ __launch_bounds__(512, 8) void splat_atomic_kernel(const float* __restrict__ src,
                                                              const float* __restrict__ flow,
                                                              float* __restrict__ out) {
    __shared__ __align__(16) u64 bins[TBINS];
    const int t  = threadIdx.x;
    const int bk = blockIdx.x, bj = blockIdx.y, bi = blockIdx.z;
    const int i0 = bi * BI, j0 = bj * BJ, k0 = bk * BK;
    const int xg0 = i0 - HL, yg0 = j0 - HL, zg0 = k0 - HL;

    {
        const float4 z4 = make_float4(0.f, 0.f, 0.f, 0.f);
        float4* b4 = reinterpret_cast<float4*>(bins);
        for (int c = t; c < TBINS * 2 / 4; c += 512) b4[c] = z4;
    }
    __syncthreads();

    {
        const int kg = (t & 7) * 4;
        const int cj = (t >> 3) & 7;
        const int ci = t >> 6;
        const int i = i0 + ci, j = j0 + cj, k = k0 + kg;
        const int off = i * WD + j * Dd + k;

        const float4 s4  = *reinterpret_cast<const float4*>(src + off);
        const float4 fx4 = *reinterpret_cast<const float4*>(flow + off);
        const float4 fy4 = *reinterpret_cast<const float4*>(flow + N + off);
        const float4 fz4 = *reinterpret_cast<const float4*>(flow + 2 * N + off);

        const float sa[4]  = {s4.x, s4.y, s4.z, s4.w};
        const float fxa[4] = {fx4.x, fx4.y, fx4.z, fx4.w};
        const float fya[4] = {fy4.x, fy4.y, fy4.z, fy4.w};
        const float fza[4] = {fz4.x, fz4.y, fz4.z, fz4.w};

#pragma unroll
        for (int q = 0; q < 4; ++q) {
            const float lx = fmaxf((float)i       + fxa[q], 0.0f);
            const float ly = fmaxf((float)j       + fya[q], 0.0f);
            const float lz = fmaxf((float)(k + q) + fza[q], 0.0f);

            const float bx = floorf(lx), by = floorf(ly), bz = floorf(lz);
            const float dx = lx - bx,    dy = ly - by,    dz = lz - bz;

            const int x0 = min((int)bx, H - 1);
            const int y0 = min((int)by, W - 1);
            const int z0 = min((int)bz, Dd - 1);
            const int x1 = min(x0 + 1, H - 1);
            const int y1 = min(y0 + 1, W - 1);
            const int z1 = min(z0 + 1, Dd - 1);

            const float s = sa[q];
            const float dyf = (y1 > y0) ? dy : 0.0f;
            const float dzf = (z1 > z0) ? dz : 0.0f;

            const int a0 = x0 - xg0, a1 = x1 - xg0;
            const int b0 = y0 - yg0;
            const int c0 = z0 - zg0;

            const bool fast = ((unsigned)a0 < (unsigned)TI) & ((unsigned)a1 < (unsigned)TI) &
                              ((unsigned)b0 < (unsigned)TJS) &
                              ((unsigned)c0 < (unsigned)TKS);

            if (__builtin_expect(fast, 1)) {
                const float w0 = s * (1.0f - dx);
                const float w1 = s * dx;
                {
                    const float m1 = w0 * dyf, m2 = w0 * dzf;
                    const float FD = m1 * dzf;
                    const float FB = m1 - FD, FC = m2 - FD;
                    const float FA = (w0 - m1) - FC;
                    atomicAdd(&bins[(a0 * TJS + b0) * TKS + c0], pack4(FA, FB, FC, FD));
                }
                {
                    const float m1 = w1 * dyf, m2 = w1 * dzf;
                    const float FD = m1 * dzf;
                    const float FB = m1 - FD, FC = m2 - FD;
                    const float FA = (w1 - m1) - FC;
                    atomicAdd(&bins[(a1 * TJS + b0) * TKS + c0], pack4(FA, FB, FC, FD));
                }
            } else {
                const float wx0 = 1.0f - dx, wy0 = 1.0f - dy, wz0 = 1.0f - dz;
                const float a00 = s * wx0 * wy0;
                const float a01 = s * wx0 * dy;
                const float a10 = s * dx * wy0;
                const float a11 = s * dx * dy;
                unsafeAtomicAdd(out + x0 * WD + y0 * Dd + z0, a00 * wz0);
                unsafeAtomicAdd(out + x0 * WD + y0 * Dd + z1, a00 * dz);
                unsafeAtomicAdd(out + x0 * WD + y1 * Dd + z0, a01 * wz0);
                unsafeAtomicAdd(out + x0 * WD + y1 * Dd + z1, a01 * dz);
                unsafeAtomicAdd(out + x1 * WD + y0 * Dd + z0, a10 * wz0);
                unsafeAtomicAdd(out + x1 * WD + y0 * Dd + z1, a10 * dz);
                unsafeAtomicAdd(out + x1 * WD + y1 * Dd + z0, a11 * wz0);
                unsafeAtomicAdd(out + x1 * WD + y1 * Dd + z1, a11 * dz);
            }
        }
    }
    __syncthreads();

    for (int c = t; c < TCELLS; c += 512) {
        const int z    = c % TK;
        const int rest = c / TK;
        const int b    = rest % TJ;
        const int a    = rest / TJ;

        const int rb = (a * TJS + b) * TKS;
        const int rm = rb - TKS;
        const bool hb = (b < TJS), hm = (b > 0);
        const bool hz = (z < TKS), hzm = (z > 0);

        const u64 Tb  = (hb && hz)  ? bins[rb + z]     : 0ull;
        const u64 Tm  = (hm && hz)  ? bins[rm + z]     : 0ull;
        const u64 Tbz = (hb && hzm) ? bins[rb + z - 1] : 0ull;
        const u64 Tmz = (hm && hzm) ? bins[rm + z - 1] : 0ull;

        if ((Tb | Tm | Tbz | Tmz) == 0ull) continue;

        const int lo0 = (int)(unsigned)Tb;
        const int f0  = (int)(short)(unsigned short)lo0;
        const int lo1 = (int)(unsigned)Tm;
        const int f1  = (lo1 - (int)(short)(unsigned short)lo1) >> 16;
        const int lo2 = (int)(unsigned)Tbz;
        const int hi2 = (int)(unsigned)(Tbz >> 32) + (lo2 < 0 ? 1 : 0);
        const int f2  = (int)(short)(unsigned short)hi2;
        const int lo3 = (int)(unsigned)Tmz;
        const int hi3 = (int)(unsigned)(Tmz >> 32) + (lo3 < 0 ? 1 : 0);
        const int f3m = (int)(short)(unsigned short)hi3;
        const int f3  = (hi3 - f3m) >> 16;

        const int vi = f0 + f1 + f2 + f3;
        if (vi != 0) {
            const int x = xg0 + a, y = yg0 + b, zz = zg0 + z;
            if (((unsigned)x < (unsigned)H) & ((unsigned)y < (unsigned)W) &
                ((unsigned)zz < (unsigned)Dd)) {
                unsafeAtomicAdd(out + x * WD + y * Dd + zz, (float)vi * (1.0f / 512.0f));
            }
        }
    }
}

extern "C" void kernel_launch(void* const* d_in, const int* in_sizes, int n_in,
                              void* d_out, int out_size, void* d_ws, size_t ws_size,
                              hipStream_t stream) {
    const float* src  = (const float*)d_in[0];
    const float* flow = (const float*)d_in[1];
    float* out = (float*)d_out;

    const dim3 block(512);
    const dim3 grid(NBK, NBJ, NBI);  // (6, 24, 24) = 3456 blocks

    if (ws_size >= REC_OFF + (size_t)REC_MIN * 8) {
        char* wsb = (char*)d_ws;
        short*    wst = (short*)wsb;
        unsigned* cnt = (unsigned*)(wsb + CNT_OFF);
        u64*      rec = (u64*)(wsb + REC_OFF);
        const unsigned rec_cap = (unsigned)(((ws_size - REC_OFF) / 8) & ~(size_t)7);

        (void)hipMemsetAsync(cnt, 0, 4, stream);  // zero the record counter only
        splat_tile_kernel<<<grid, block, 0, stream>>>(src, flow, wst, rec, cnt, rec_cap);
        gather_tiles_kernel<<<(N / 4 + 255) / 256, 256, 0, stream>>>(wst, out);
        apply_records_kernel<<<1024, 256, 0, stream>>>(rec, cnt, rec_cap, out);
    } else {
        (void)hipMemsetAsync(out, 0, (size_t)N * sizeof(float), stream);
        splat_atomic_kernel<<<grid, block, 0, stream>>>(src, flow, out);
    }
}

// Round 20
// 112.664 us; speedup vs baseline: 6.1379x; 6.1379x over previous
//
#include <hip/hip_runtime.h>

// R20: R19 with block-aggregated record reservation. R19's per-wave
// atomicAdd(rec_cnt,8) on ONE address serialized the whole device (A=631us,
// VALU 5%). Outlier records now stage in LDS (1024 slots; expected ~25/block);
// ONE global atomicAdd per block reserves space; coalesced copy-out.
// Overflow (>1024) spills via direct global reservation (practically never).
// Reference semantics (exact):
//   locs = max(grid + flow, 0)
//   delta = locs - floor(locs)           (from UNclamped floor)
//   base  = min((int)floor(locs), dim-1)
//   corner per axis = min(base + {0,1}, dim-1)   (collapsed corners add twice)

typedef unsigned long long u64;

constexpr int H = 192, W = 192, Dd = 192;
constexpr int N = H * W * Dd;
constexpr int WD = W * Dd;

constexpr int BI = 8, BJ = 8, BK = 32;
constexpr int HL = 2;
constexpr int TI = BI + 2 * HL;              // 12
constexpr int TJ = BJ + 2 * HL;              // 12
constexpr int TK = BK + 2 * HL;              // 36 (div by 4 -> aligned quads)
constexpr int TJS = TJ - 1;                  // 11
constexpr int TKS = TK - 1;                  // 35
constexpr int TBINS = TI * TJS * TKS;        // 4620 u64 = 36.96 KB
constexpr int TCELLS = TI * TJ * TK;         // 5184 cells per tile
constexpr int NBI = H / BI, NBJ = W / BJ, NBK = Dd / BK;   // 24,24,6
constexpr int NBLK = NBI * NBJ * NBK;        // 3456
constexpr int STAGE_CAP = 1024;              // LDS record slots (8 KB)

// ws layout: [i16 tiles][16B-aligned counter][records (u64 each)]
constexpr size_t TILE_BYTES = (size_t)NBLK * TCELLS * sizeof(short);   // 35.83 MB
constexpr size_t CNT_OFF    = (TILE_BYTES + 15) & ~(size_t)15;
constexpr size_t REC_OFF    = CNT_OFF + 16;
constexpr unsigned REC_MIN  = 2u * 1024 * 1024;   // require >= 2M record slots

constexpr float SCALE      = 512.0f;         // bin scale 2^9
constexpr float INV_SCALE2 = 1.0f / 256.0f;  // ws scale 2^8

__device__ __forceinline__ u64 pack4(float fa, float fb, float fc, float fd) {
    const int d0 = (int)rintf(fa * SCALE);
    const int d1 = (int)rintf(fb * SCALE);
    const int d2 = (int)rintf(fc * SCALE);
    const int d3 = (int)rintf(fd * SCALE);
    const int lo = d0 + (d1 << 16);
    const int hi = d2 + (d3 << 16) - (lo < 0 ? 1 : 0);
    return ((u64)(unsigned)hi << 32) | (unsigned)lo;
}

__device__ __forceinline__ u64 pack_rec(int idx, float v) {
    return ((u64)__float_as_uint(v) << 32) | (unsigned)idx;
}

// ---- Kernel A: scatter -> bins; outliers -> LDS-staged record list; tile -> i16 ws ----
__global__ __launch_bounds__(512) void splat_tile_kernel(const float* __restrict__ src,
                                                         const float* __restrict__ flow,
                                                         short* __restrict__ wst,
                                                         u64* __restrict__ rec,
                                                         unsigned* __restrict__ rec_cnt,
                                                         unsigned rec_cap) {
    __shared__ __align__(16) u64 bins[TBINS];
    __shared__ __align__(16) u64 stage[STAGE_CAP];
    __shared__ unsigned loc_cnt;
    __shared__ unsigned glob_base;

    const int t  = threadIdx.x;
    const int bk = blockIdx.x, bj = blockIdx.y, bi = blockIdx.z;
    const int i0 = bi * BI, j0 = bj * BJ, k0 = bk * BK;
    const int xg0 = i0 - HL, yg0 = j0 - HL, zg0 = k0 - HL;

    if (t == 0) loc_cnt = 0;
    {
        const float4 z4 = make_float4(0.f, 0.f, 0.f, 0.f);
        float4* b4 = reinterpret_cast<float4*>(bins);
        for (int c = t; c < TBINS * 2 / 4; c += 512) b4[c] = z4;
    }
    __syncthreads();

    // --- scatter: 2048 voxels, 4 consecutive-z per thread ---
    {
        const int kg = (t & 7) * 4;
        const int cj = (t >> 3) & 7;
        const int ci = t >> 6;
        const int i = i0 + ci, j = j0 + cj, k = k0 + kg;
        const int off = i * WD + j * Dd + k;

        const float4 s4  = *reinterpret_cast<const float4*>(src + off);
        const float4 fx4 = *reinterpret_cast<const float4*>(flow + off);
        const float4 fy4 = *reinterpret_cast<const float4*>(flow + N + off);
        const float4 fz4 = *reinterpret_cast<const float4*>(flow + 2 * N + off);

        const float sa[4]  = {s4.x, s4.y, s4.z, s4.w};
        const float fxa[4] = {fx4.x, fx4.y, fx4.z, fx4.w};
        const float fya[4] = {fy4.x, fy4.y, fy4.z, fy4.w};
        const float fza[4] = {fz4.x, fz4.y, fz4.z, fz4.w};

#pragma unroll
        for (int q = 0; q < 4; ++q) {
            const float lx = fmaxf((float)i       + fxa[q], 0.0f);
            const float ly = fmaxf((float)j       + fya[q], 0.0f);
            const float lz = fmaxf((float)(k + q) + fza[q], 0.0f);

            const float bx = floorf(lx), by = floorf(ly), bz = floorf(lz);
            const float dx = lx - bx,    dy = ly - by,    dz = lz - bz;

            const int x0 = min((int)bx, H - 1);
            const int y0 = min((int)by, W - 1);
            const int z0 = min((int)bz, Dd - 1);
            const int x1 = min(x0 + 1, H - 1);
            const int y1 = min(y0 + 1, W - 1);
            const int z1 = min(z0 + 1, Dd - 1);

            const float s = sa[q];
            const float dyf = (y1 > y0) ? dy : 0.0f;   // collapse -> full weight in clamped cell
            const float dzf = (z1 > z0) ? dz : 0.0f;

            const int a0 = x0 - xg0, a1 = x1 - xg0;
            const int b0 = y0 - yg0;
            const int c0 = z0 - zg0;

            const bool fast = ((unsigned)a0 < (unsigned)TI) & ((unsigned)a1 < (unsigned)TI) &
                              ((unsigned)b0 < (unsigned)TJS) &
                              ((unsigned)c0 < (unsigned)TKS);

            if (__builtin_expect(fast, 1)) {
                const float w0 = s * (1.0f - dx);
                const float w1 = s * dx;
                {
                    const float m1 = w0 * dyf, m2 = w0 * dzf;
                    const float FD = m1 * dzf;
                    const float FB = m1 - FD, FC = m2 - FD;
                    const float FA = (w0 - m1) - FC;
                    atomicAdd(&bins[(a0 * TJS + b0) * TKS + c0], pack4(FA, FB, FC, FD));
                }
                {
                    const float m1 = w1 * dyf, m2 = w1 * dzf;
                    const float FD = m1 * dzf;
                    const float FB = m1 - FD, FC = m2 - FD;
                    const float FA = (w1 - m1) - FC;
                    atomicAdd(&bins[(a1 * TJS + b0) * TKS + c0], pack4(FA, FB, FC, FD));
                }
            } else {
                // outlier: stage 8 corner records in LDS (block-aggregated
                // global reservation happens once, after the barrier)
                const float wx0 = 1.0f - dx, wy0 = 1.0f - dy, wz0 = 1.0f - dz;
                const float a00 = s * wx0 * wy0;
                const float a01 = s * wx0 * dy;
                const float a10 = s * dx * wy0;
                const float a11 = s * dx * dy;
                const unsigned base = atomicAdd(&loc_cnt, 8u);   // LDS atomic: cheap
                if (base + 8u <= (unsigned)STAGE_CAP) {
                    u64* r = stage + base;
                    r[0] = pack_rec(x0 * WD + y0 * Dd + z0, a00 * wz0);
                    r[1] = pack_rec(x0 * WD + y0 * Dd + z1, a00 * dz);
                    r[2] = pack_rec(x0 * WD + y1 * Dd + z0, a01 * wz0);
                    r[3] = pack_rec(x0 * WD + y1 * Dd + z1, a01 * dz);
                    r[4] = pack_rec(x1 * WD + y0 * Dd + z0, a10 * wz0);
                    r[5] = pack_rec(x1 * WD + y0 * Dd + z1, a10 * dz);
                    r[6] = pack_rec(x1 * WD + y1 * Dd + z0, a11 * wz0);
                    r[7] = pack_rec(x1 * WD + y1 * Dd + z1, a11 * dz);
                } else {
                    // overflow spill (practically never): direct global reservation
                    const unsigned gb = atomicAdd(rec_cnt, 8u);
                    if (gb + 8u <= rec_cap) {
                        u64* r = rec + gb;
                        r[0] = pack_rec(x0 * WD + y0 * Dd + z0, a00 * wz0);
                        r[1] = pack_rec(x0 * WD + y0 * Dd + z1, a00 * dz);
                        r[2] = pack_rec(x0 * WD + y1 * Dd + z0, a01 * wz0);
                        r[3] = pack_rec(x0 * WD + y1 * Dd + z1, a01 * dz);
                        r[4] = pack_rec(x1 * WD + y0 * Dd + z0, a10 * wz0);
                        r[5] = pack_rec(x1 * WD + y0 * Dd + z1, a10 * dz);
                        r[6] = pack_rec(x1 * WD + y1 * Dd + z0, a11 * wz0);
                        r[7] = pack_rec(x1 * WD + y1 * Dd + z1, a11 * dz);
                    }
                }
            }
        }
    }
    __syncthreads();

    // --- one global reservation per block, then coalesced record copy-out ---
    const unsigned nrec = min(loc_cnt, (unsigned)STAGE_CAP);
    if (t == 0 && nrec > 0) glob_base = atomicAdd(rec_cnt, nrec);
    __syncthreads();
    if (nrec > 0) {
        const unsigned gb = glob_base;
        for (unsigned r = t; r < nrec; r += 512) {
            if (gb + r < rec_cap) rec[gb + r] = stage[r];
        }
    }

    // --- quad-decode epilogue: 4 z-cells -> one short4 ws store (scale 2^8) ---
    short* wt = wst + (size_t)((bi * NBJ + bj) * NBK + bk) * TCELLS;
    for (int qd = t; qd < TCELLS / 4; qd += 512) {
        const int c0  = qd * 4;
        const int z0q = c0 % TK;
        const int row = c0 / TK;
        const int b   = row % TJ;
        const int a   = row / TJ;

        const int rb = (a * TJS + b) * TKS;
        const int rm = rb - TKS;
        const bool hb = (b < TJS), hm = (b > 0);

        u64 tb[5], tm[5];
#pragma unroll
        for (int d = 0; d < 5; ++d) {
            const int zi = z0q - 1 + d;
            const bool zok = ((unsigned)zi < (unsigned)TKS);
            tb[d] = (hb && zok) ? bins[rb + zi] : 0ull;
            tm[d] = (hm && zok) ? bins[rm + zi] : 0ull;
        }

        int A0[5], C2[5], B1[5], D3[5];
#pragma unroll
        for (int d = 0; d < 5; ++d) {
            const int lob = (int)(unsigned)tb[d];
            const int hib = (int)(unsigned)(tb[d] >> 32) + (lob < 0 ? 1 : 0);
            A0[d] = (int)(short)(unsigned short)lob;          // F_A
            C2[d] = (int)(short)(unsigned short)hib;          // F_C
            const int lom = (int)(unsigned)tm[d];
            const int him = (int)(unsigned)(tm[d] >> 32) + (lom < 0 ? 1 : 0);
            const int f0m = (int)(short)(unsigned short)lom;
            B1[d] = (lom - f0m) >> 16;                        // F_B
            const int f2m = (int)(short)(unsigned short)him;
            D3[d] = (him - f2m) >> 16;                        // F_D
        }

        short4 sv;
        sv.x = (short)((A0[1] + B1[1] + C2[0] + D3[0] + 1) >> 1);
        sv.y = (short)((A0[2] + B1[2] + C2[1] + D3[1] + 1) >> 1);
        sv.z = (short)((A0[3] + B1[3] + C2[2] + D3[2] + 1) >> 1);
        sv.w = (short)((A0[4] + B1[4] + C2[3] + D3[3] + 1) >> 1);
        *reinterpret_cast<short4*>(wt + c0) = sv;
    }
}

// ---- Kernel B: out = gather of covering tile cells (plain store) ----
__global__ __launch_bounds__(256) void gather_tiles_kernel(const short* __restrict__ ws,
                                                           float* __restrict__ out) {
    const int tid = blockIdx.x * 256 + threadIdx.x;
    const int n0 = tid * 4;
    if (n0 >= N) return;

    const int i   = n0 / WD;
    const int rem = n0 - i * WD;
    const int j   = rem / Dd;
    const int z0  = rem - j * Dd;

    int acc[4] = {0, 0, 0, 0};

    const int biA = (i + HL) >> 3;
    const int bjA = (j + HL) >> 3;

#pragma unroll
    for (int dbi = 0; dbi < 2; ++dbi) {
        const int bi = biA - dbi;
        if ((unsigned)bi >= (unsigned)NBI) continue;
        const int a = i - (bi * BI - HL);
        if ((unsigned)a >= (unsigned)TI) continue;
#pragma unroll
        for (int dbj = 0; dbj < 2; ++dbj) {
            const int bj = bjA - dbj;
            if ((unsigned)bj >= (unsigned)NBJ) continue;
            const int b = j - (bj * BJ - HL);
            if ((unsigned)b >= (unsigned)TJ) continue;

            const short* pbase = ws + (size_t)((bi * NBJ + bj) * NBK) * TCELLS
                               + (a * TJ + b) * TK;
#pragma unroll
            for (int q = 0; q < 4; ++q) {
                const int z = z0 + q;
                const int bkA = (z + HL) >> 5;
#pragma unroll
                for (int dbk = 0; dbk < 2; ++dbk) {
                    const int bk = bkA - dbk;
                    if ((unsigned)bk >= (unsigned)NBK) continue;
                    const int c = z - (bk * BK - HL);
                    if ((unsigned)c >= (unsigned)TK) continue;
                    acc[q] += pbase[(size_t)bk * TCELLS + c];
                }
            }
        }
    }
    float4 r;
    r.x = (float)acc[0] * INV_SCALE2;
    r.y = (float)acc[1] * INV_SCALE2;
    r.z = (float)acc[2] * INV_SCALE2;
    r.w = (float)acc[3] * INV_SCALE2;
    *reinterpret_cast<float4*>(out + n0) = r;
}

// ---- Kernel C: apply outlier records (runs after B) ----
__global__ __launch_bounds__(256) void apply_records_kernel(const u64* __restrict__ rec,
                                                            const unsigned* __restrict__ rec_cnt,
                                                            unsigned rec_cap,
                                                            float* __restrict__ out) {
    const unsigned n = min(*rec_cnt, rec_cap);
    const unsigned stride = gridDim.x * 256;
    for (unsigned idx = blockIdx.x * 256 + threadIdx.x; idx < n; idx += stride) {
        const u64 r = rec[idx];
        unsafeAtomicAdd(out + (unsigned)(r & 0xffffffffu), __uint_as_float((unsigned)(r >> 32)));
    }
}

// ---- fallback: single kernel with atomic flush (requires memset of out) ----
__global__ __launch_bounds__(512, 8) void splat_atomic_kernel(const float* __restrict__ src,
                                                              const float* __restrict__ flow,
                                                              float* __restrict__ out) {
    __shared__ __align__(16) u64 bins[TBINS];
    const int t  = threadIdx.x;
    const int bk = blockIdx.x, bj = blockIdx.y, bi = blockIdx.z;
    const int i0 = bi * BI, j0 = bj * BJ, k0 = bk * BK;
    const int xg0 = i0 - HL, yg0 = j0 - HL, zg0 = k0 - HL;

    {
        const float4 z4 = make_float4(0.f, 0.f, 0.f, 0.f);
        float4* b4 = reinterpret_cast<float4*>(bins);
        for (int c = t; c < TBINS * 2 / 4; c += 512) b4[c] = z4;
    }
    __syncthreads();

    {
        const int kg = (t & 7) * 4;
        const int cj = (t >> 3) & 7;
        const int ci = t >> 6;
        const int i = i0 + ci, j = j0 + cj, k = k0 + kg;
        const int off = i * WD + j * Dd + k;

        const float4 s4  = *reinterpret_cast<const float4*>(src + off);
        const float4 fx4 = *reinterpret_cast<const float4*>(flow + off);
        const float4 fy4 = *reinterpret_cast<const float4*>(flow + N + off);
        const float4 fz4 = *reinterpret_cast<const float4*>(flow + 2 * N + off);

        const float sa[4]  = {s4.x, s4.y, s4.z, s4.w};
        const float fxa[4] = {fx4.x, fx4.y, fx4.z, fx4.w};
        const float fya[4] = {fy4.x, fy4.y, fy4.z, fy4.w};
        const float fza[4] = {fz4.x, fz4.y, fz4.z, fz4.w};

#pragma unroll
        for (int q = 0; q < 4; ++q) {
            const float lx = fmaxf((float)i       + fxa[q], 0.0f);
            const float ly = fmaxf((float)j       + fya[q], 0.0f);
            const float lz = fmaxf((float)(k + q) + fza[q], 0.0f);

            const float bx = floorf(lx), by = floorf(ly), bz = floorf(lz);
            const float dx = lx - bx,    dy = ly - by,    dz = lz - bz;

            const int x0 = min((int)bx, H - 1);
            const int y0 = min((int)by, W - 1);
            const int z0 = min((int)bz, Dd - 1);
            const int x1 = min(x0 + 1, H - 1);
            const int y1 = min(y0 + 1, W - 1);
            const int z1 = min(z0 + 1, Dd - 1);

            const float s = sa[q];
            const float dyf = (y1 > y0) ? dy : 0.0f;
            const float dzf = (z1 > z0) ? dz : 0.0f;

            const int a0 = x0 - xg0, a1 = x1 - xg0;
            const int b0 = y0 - yg0;
            const int c0 = z0 - zg0;

            const bool fast = ((unsigned)a0 < (unsigned)TI) & ((unsigned)a1 < (unsigned)TI) &
                              ((unsigned)b0 < (unsigned)TJS) &
                              ((unsigned)c0 < (unsigned)TKS);

            if (__builtin_expect(fast, 1)) {
                const float w0 = s * (1.0f - dx);
                const float w1 = s * dx;
                {
                    const float m1 = w0 * dyf, m2 = w0 * dzf;
                    const float FD = m1 * dzf;
                    const float FB = m1 - FD, FC = m2 - FD;
                    const float FA = (w0 - m1) - FC;
                    atomicAdd(&bins[(a0 * TJS + b0) * TKS + c0], pack4(FA, FB, FC, FD));
                }
                {
                    const float m1 = w1 * dyf, m2 = w1 * dzf;
                    const float FD = m1 * dzf;
                    const float FB = m1 - FD, FC = m2 - FD;
                    const float FA = (w1 - m1) - FC;
                    atomicAdd(&bins[(a1 * TJS + b0) * TKS + c0], pack4(FA, FB, FC, FD));
                }
            } else {
                const float wx0 = 1.0f - dx, wy0 = 1.0f - dy, wz0 = 1.0f - dz;
                const float a00 = s * wx0 * wy0;
                const float a01 = s * wx0 * dy;
                const float a10 = s * dx * wy0;
                const float a11 = s * dx * dy;
                unsafeAtomicAdd(out + x0 * WD + y0 * Dd + z0, a00 * wz0);
                unsafeAtomicAdd(out + x0 * WD + y0 * Dd + z1, a00 * dz);
                unsafeAtomicAdd(out + x0 * WD + y1 * Dd + z0, a01 * wz0);
                unsafeAtomicAdd(out + x0 * WD + y1 * Dd + z1, a01 * dz);
                unsafeAtomicAdd(out + x1 * WD + y0 * Dd + z0, a10 * wz0);
                unsafeAtomicAdd(out + x1 * WD + y0 * Dd + z1, a10 * dz);
                unsafeAtomicAdd(out + x1 * WD + y1 * Dd + z0, a11 * wz0);
                unsafeAtomicAdd(out + x1 * WD + y1 * Dd + z1, a11 * dz);
            }
        }
    }
    __syncthreads();

    for (int c = t; c < TCELLS; c += 512) {
        const int z    = c % TK;
        const int rest = c / TK;
        const int b    = rest % TJ;
        const int a    = rest / TJ;

        const int rb = (a * TJS + b) * TKS;
        const int rm = rb - TKS;
        const bool hb = (b < TJS), hm = (b > 0);
        const bool hz = (z < TKS), hzm = (z > 0);

        const u64 Tb  = (hb && hz)  ? bins[rb + z]     : 0ull;
        const u64 Tm  = (hm && hz)  ? bins[rm + z]     : 0ull;
        const u64 Tbz = (hb && hzm) ? bins[rb + z - 1] : 0ull;
        const u64 Tmz = (hm && hzm) ? bins[rm + z - 1] : 0ull;

        if ((Tb | Tm | Tbz | Tmz) == 0ull) continue;

        const int lo0 = (int)(unsigned)Tb;
        const int f0  = (int)(short)(unsigned short)lo0;
        const int lo1 = (int)(unsigned)Tm;
        const int f1  = (lo1 - (int)(short)(unsigned short)lo1) >> 16;
        const int lo2 = (int)(unsigned)Tbz;
        const int hi2 = (int)(unsigned)(Tbz >> 32) + (lo2 < 0 ? 1 : 0);
        const int f2  = (int)(short)(unsigned short)hi2;
        const int lo3 = (int)(unsigned)Tmz;
        const int hi3 = (int)(unsigned)(Tmz >> 32) + (lo3 < 0 ? 1 : 0);
        const int f3m = (int)(short)(unsigned short)hi3;
        const int f3  = (hi3 - f3m) >> 16;

        const int vi = f0 + f1 + f2 + f3;
        if (vi != 0) {
            const int x = xg0 + a, y = yg0 + b, zz = zg0 + z;
            if (((unsigned)x < (unsigned)H) & ((unsigned)y < (unsigned)W) &
                ((unsigned)zz < (unsigned)Dd)) {
                unsafeAtomicAdd(out + x * WD + y * Dd + zz, (float)vi * (1.0f / 512.0f));
            }
        }
    }
}

extern "C" void kernel_launch(void* const* d_in, const int* in_sizes, int n_in,
                              void* d_out, int out_size, void* d_ws, size_t ws_size,
                              hipStream_t stream) {
    const float* src  = (const float*)d_in[0];
    const float* flow = (const float*)d_in[1];
    float* out = (float*)d_out;

    const dim3 block(512);
    const dim3 grid(NBK, NBJ, NBI);  // (6, 24, 24) = 3456 blocks

    if (ws_size >= REC_OFF + (size_t)REC_MIN * 8) {
        char* wsb = (char*)d_ws;
        short*    wst = (short*)wsb;
        unsigned* cnt = (unsigned*)(wsb + CNT_OFF);
        u64*      rec = (u64*)(wsb + REC_OFF);
        const unsigned rec_cap = (unsigned)(((ws_size - REC_OFF) / 8) & ~(size_t)7);

        (void)hipMemsetAsync(cnt, 0, 4, stream);  // zero the record counter only
        splat_tile_kernel<<<grid, block, 0, stream>>>(src, flow, wst, rec, cnt, rec_cap);
        gather_tiles_kernel<<<(N / 4 + 255) / 256, 256, 0, stream>>>(wst, out);
        apply_records_kernel<<<1024, 256, 0, stream>>>(rec, cnt, rec_cap, out);
    } else {
        (void)hipMemsetAsync(out, 0, (size_t)N * sizeof(float), stream);
        splat_atomic_kernel<<<grid, block, 0, stream>>>(src, flow, out);
    }
}

// Round 21
// 89.108 us; speedup vs baseline: 7.7604x; 1.2643x over previous
//
#include <hip/hip_runtime.h>

// R21 = R17 reverted (best: 89.3us). R20 post-mortem: outlier atomics are FREE
// when inline in A (overlapped); a standalone apply-records kernel costs ~30us.
// Structure: memset(out) + A(scatter->LDS bins, inline outlier atomics to out,
// quad-decode -> i16 ws tiles) + B(out += gather of covering tile cells).
// Reference semantics (exact):
//   locs = max(grid + flow, 0)
//   delta = locs - floor(locs)           (from UNclamped floor)
//   base  = min((int)floor(locs), dim-1)
//   corner per axis = min(base + {0,1}, dim-1)   (collapsed corners add twice)

typedef unsigned long long u64;

constexpr int H = 192, W = 192, Dd = 192;
constexpr int N = H * W * Dd;
constexpr int WD = W * Dd;

constexpr int BI = 8, BJ = 8, BK = 32;
constexpr int HL = 2;
constexpr int TI = BI + 2 * HL;              // 12
constexpr int TJ = BJ + 2 * HL;              // 12
constexpr int TK = BK + 2 * HL;              // 36 (div by 4 -> aligned quads)
constexpr int TJS = TJ - 1;                  // 11
constexpr int TKS = TK - 1;                  // 35
constexpr int TBINS = TI * TJS * TKS;        // 4620 u64 = 36.96 KB
constexpr int TCELLS = TI * TJ * TK;         // 5184 cells per tile
constexpr int NBI = H / BI, NBJ = W / BJ, NBK = Dd / BK;   // 24,24,6
constexpr int NBLK = NBI * NBJ * NBK;        // 3456
constexpr size_t WS_NEEDED = (size_t)NBLK * TCELLS * sizeof(short);  // 35.8 MB

constexpr float SCALE      = 512.0f;         // bin scale 2^9
constexpr float INV_SCALE2 = 1.0f / 256.0f;  // ws scale 2^8

__device__ __forceinline__ u64 pack4(float fa, float fb, float fc, float fd) {
    const int d0 = (int)rintf(fa * SCALE);
    const int d1 = (int)rintf(fb * SCALE);
    const int d2 = (int)rintf(fc * SCALE);
    const int d3 = (int)rintf(fd * SCALE);
    const int lo = d0 + (d1 << 16);
    const int hi = d2 + (d3 << 16) - (lo < 0 ? 1 : 0);
    return ((u64)(unsigned)hi << 32) | (unsigned)lo;
}

__device__ __forceinline__ int fld0(u64 T) {
    return (int)(short)(unsigned short)(unsigned)T;
}
__device__ __forceinline__ int fld1(u64 T) {
    const int lo = (int)(unsigned)T;
    return (lo - (int)(short)(unsigned short)lo) >> 16;
}
__device__ __forceinline__ int fld2(u64 T) {
    const int lo = (int)(unsigned)T;
    const int hi = (int)(unsigned)(T >> 32) + (lo < 0 ? 1 : 0);
    return (int)(short)(unsigned short)hi;
}
__device__ __forceinline__ int fld3(u64 T) {
    const int lo = (int)(unsigned)T;
    const int hi = (int)(unsigned)(T >> 32) + (lo < 0 ? 1 : 0);
    return (hi - (int)(short)(unsigned short)hi) >> 16;
}

// ---- shared scatter body (fast path -> LDS bins; outliers -> out atomics) ----
__device__ __forceinline__ void scatter_phase(const float* __restrict__ src,
                                              const float* __restrict__ flow,
                                              float* __restrict__ out,
                                              u64* bins, int t,
                                              int i0, int j0, int k0,
                                              int xg0, int yg0, int zg0) {
    const int kg = (t & 7) * 4;
    const int cj = (t >> 3) & 7;
    const int ci = t >> 6;
    const int i = i0 + ci, j = j0 + cj, k = k0 + kg;
    const int off = i * WD + j * Dd + k;

    const float4 s4  = *reinterpret_cast<const float4*>(src + off);
    const float4 fx4 = *reinterpret_cast<const float4*>(flow + off);
    const float4 fy4 = *reinterpret_cast<const float4*>(flow + N + off);
    const float4 fz4 = *reinterpret_cast<const float4*>(flow + 2 * N + off);

    const float sa[4]  = {s4.x, s4.y, s4.z, s4.w};
    const float fxa[4] = {fx4.x, fx4.y, fx4.z, fx4.w};
    const float fya[4] = {fy4.x, fy4.y, fy4.z, fy4.w};
    const float fza[4] = {fz4.x, fz4.y, fz4.z, fz4.w};

#pragma unroll
    for (int q = 0; q < 4; ++q) {
        const float lx = fmaxf((float)i       + fxa[q], 0.0f);
        const float ly = fmaxf((float)j       + fya[q], 0.0f);
        const float lz = fmaxf((float)(k + q) + fza[q], 0.0f);

        const float bx = floorf(lx), by = floorf(ly), bz = floorf(lz);
        const float dx = lx - bx,    dy = ly - by,    dz = lz - bz;

        const int x0 = min((int)bx, H - 1);
        const int y0 = min((int)by, W - 1);
        const int z0 = min((int)bz, Dd - 1);
        const int x1 = min(x0 + 1, H - 1);
        const int y1 = min(y0 + 1, W - 1);
        const int z1 = min(z0 + 1, Dd - 1);

        const float s = sa[q];
        const float dyf = (y1 > y0) ? dy : 0.0f;   // collapse -> full weight in clamped cell
        const float dzf = (z1 > z0) ? dz : 0.0f;

        const int a0 = x0 - xg0, a1 = x1 - xg0;
        const int b0 = y0 - yg0;
        const int c0 = z0 - zg0;

        const bool fast = ((unsigned)a0 < (unsigned)TI) & ((unsigned)a1 < (unsigned)TI) &
                          ((unsigned)b0 < (unsigned)TJS) &
                          ((unsigned)c0 < (unsigned)TKS);

        if (__builtin_expect(fast, 1)) {
            const float w0 = s * (1.0f - dx);
            const float w1 = s * dx;
            {
                const float m1 = w0 * dyf, m2 = w0 * dzf;
                const float FD = m1 * dzf;
                const float FB = m1 - FD, FC = m2 - FD;
                const float FA = (w0 - m1) - FC;
                atomicAdd(&bins[(a0 * TJS + b0) * TKS + c0], pack4(FA, FB, FC, FD));
            }
            {
                const float m1 = w1 * dyf, m2 = w1 * dzf;
                const float FD = m1 * dzf;
                const float FB = m1 - FD, FC = m2 - FD;
                const float FA = (w1 - m1) - FC;
                atomicAdd(&bins[(a1 * TJS + b0) * TKS + c0], pack4(FA, FB, FC, FD));
            }
        } else {
            const float wx0 = 1.0f - dx, wy0 = 1.0f - dy, wz0 = 1.0f - dz;
            const float a00 = s * wx0 * wy0;
            const float a01 = s * wx0 * dy;
            const float a10 = s * dx * wy0;
            const float a11 = s * dx * dy;
            unsafeAtomicAdd(out + x0 * WD + y0 * Dd + z0, a00 * wz0);
            unsafeAtomicAdd(out + x0 * WD + y0 * Dd + z1, a00 * dz);
            unsafeAtomicAdd(out + x0 * WD + y1 * Dd + z0, a01 * wz0);
            unsafeAtomicAdd(out + x0 * WD + y1 * Dd + z1, a01 * dz);
            unsafeAtomicAdd(out + x1 * WD + y0 * Dd + z0, a10 * wz0);
            unsafeAtomicAdd(out + x1 * WD + y0 * Dd + z1, a10 * dz);
            unsafeAtomicAdd(out + x1 * WD + y1 * Dd + z0, a11 * wz0);
            unsafeAtomicAdd(out + x1 * WD + y1 * Dd + z1, a11 * dz);
        }
    }
}

// ---- Kernel A: scatter + quad-decode + short4 store tile to ws (i16) ----
__global__ __launch_bounds__(512, 8) void splat_tile_kernel(const float* __restrict__ src,
                                                            const float* __restrict__ flow,
                                                            float* __restrict__ out,
                                                            short* __restrict__ ws) {
    __shared__ __align__(16) u64 bins[TBINS];

    const int t  = threadIdx.x;
    const int bk = blockIdx.x, bj = blockIdx.y, bi = blockIdx.z;
    const int i0 = bi * BI, j0 = bj * BJ, k0 = bk * BK;
    const int xg0 = i0 - HL, yg0 = j0 - HL;

    {
        const float4 z4 = make_float4(0.f, 0.f, 0.f, 0.f);
        float4* b4 = reinterpret_cast<float4*>(bins);
        for (int c = t; c < TBINS * 2 / 4; c += 512) b4[c] = z4;
    }
    __syncthreads();

    scatter_phase(src, flow, out, bins, t, i0, j0, k0, xg0, yg0, k0 - HL);
    __syncthreads();

    // quad-decode: thread owns 4 consecutive z-cells -> one short4 store.
    // cell(z) = fld0(rb[z]) + fld1(rm[z]) + fld2(rb[z-1]) + fld3(rm[z-1])
    short* wt = ws + (size_t)((bi * NBJ + bj) * NBK + bk) * TCELLS;
    for (int qd = t; qd < TCELLS / 4; qd += 512) {
        const int c0  = qd * 4;
        const int z0q = c0 % TK;           // 0,4,...,32 (quads never cross rows)
        const int row = c0 / TK;
        const int b   = row % TJ;
        const int a   = row / TJ;

        const int rb = (a * TJS + b) * TKS;
        const int rm = rb - TKS;
        const bool hb = (b < TJS), hm = (b > 0);

        u64 tb[5], tm[5];
#pragma unroll
        for (int d = 0; d < 5; ++d) {
            const int zi = z0q - 1 + d;
            const bool zok = ((unsigned)zi < (unsigned)TKS);
            tb[d] = (hb && zok) ? bins[rb + zi] : 0ull;
            tm[d] = (hm && zok) ? bins[rm + zi] : 0ull;
        }

        int A0[5], C2[5], B1[5], D3[5];
#pragma unroll
        for (int d = 0; d < 5; ++d) {
            const int lob = (int)(unsigned)tb[d];
            const int hib = (int)(unsigned)(tb[d] >> 32) + (lob < 0 ? 1 : 0);
            A0[d] = (int)(short)(unsigned short)lob;          // F_A
            C2[d] = (int)(short)(unsigned short)hib;          // F_C
            const int lom = (int)(unsigned)tm[d];
            const int him = (int)(unsigned)(tm[d] >> 32) + (lom < 0 ? 1 : 0);
            const int f0m = (int)(short)(unsigned short)lom;
            B1[d] = (lom - f0m) >> 16;                        // F_B
            const int f2m = (int)(short)(unsigned short)him;
            D3[d] = (him - f2m) >> 16;                        // F_D
        }

        // scale 2^9 -> 2^8 with rounding; |result| <= ~10K, fits i16
        short4 sv;
        sv.x = (short)((A0[1] + B1[1] + C2[0] + D3[0] + 1) >> 1);
        sv.y = (short)((A0[2] + B1[2] + C2[1] + D3[1] + 1) >> 1);
        sv.z = (short)((A0[3] + B1[3] + C2[2] + D3[2] + 1) >> 1);
        sv.w = (short)((A0[4] + B1[4] + C2[3] + D3[3] + 1) >> 1);
        *reinterpret_cast<short4*>(wt + c0) = sv;
    }
}

// ---- Kernel B: gather <=8 covering tile cells (i32 sum) + outlier deposits ----
__global__ __launch_bounds__(256) void gather_tiles_kernel(const short* __restrict__ ws,
                                                           float* __restrict__ out) {
    const int tid = blockIdx.x * 256 + threadIdx.x;
    const int n0 = tid * 4;
    if (n0 >= N) return;

    const int i   = n0 / WD;
    const int rem = n0 - i * WD;
    const int j   = rem / Dd;
    const int z0  = rem - j * Dd;          // multiple of 4

    const float4 o4 = *reinterpret_cast<const float4*>(out + n0);  // outlier deposits
    int acc[4] = {0, 0, 0, 0};

    const int biA = (i + HL) >> 3;
    const int bjA = (j + HL) >> 3;

#pragma unroll
    for (int dbi = 0; dbi < 2; ++dbi) {
        const int bi = biA - dbi;
        if ((unsigned)bi >= (unsigned)NBI) continue;
        const int a = i - (bi * BI - HL);
        if ((unsigned)a >= (unsigned)TI) continue;
#pragma unroll
        for (int dbj = 0; dbj < 2; ++dbj) {
            const int bj = bjA - dbj;
            if ((unsigned)bj >= (unsigned)NBJ) continue;
            const int b = j - (bj * BJ - HL);
            if ((unsigned)b >= (unsigned)TJ) continue;

            const short* pbase = ws + (size_t)((bi * NBJ + bj) * NBK) * TCELLS
                               + (a * TJ + b) * TK;
#pragma unroll
            for (int q = 0; q < 4; ++q) {
                const int z = z0 + q;
                const int bkA = (z + HL) >> 5;
#pragma unroll
                for (int dbk = 0; dbk < 2; ++dbk) {
                    const int bk = bkA - dbk;
                    if ((unsigned)bk >= (unsigned)NBK) continue;
                    const int c = z - (bk * BK - HL);
                    if ((unsigned)c >= (unsigned)TK) continue;
                    acc[q] += pbase[(size_t)bk * TCELLS + c];
                }
            }
        }
    }
    float4 r;
    r.x = o4.x + (float)acc[0] * INV_SCALE2;
    r.y = o4.y + (float)acc[1] * INV_SCALE2;
    r.z = o4.z + (float)acc[2] * INV_SCALE2;
    r.w = o4.w + (float)acc[3] * INV_SCALE2;
    *reinterpret_cast<float4*>(out + n0) = r;
}

// ---- fallback: single-kernel atomic flush ----
__global__ __launch_bounds__(512, 8) void splat_atomic_kernel(const float* __restrict__ src,
                                                              const float* __restrict__ flow,
                                                              float* __restrict__ out) {
    __shared__ __align__(16) u64 bins[TBINS];
    const int t  = threadIdx.x;
    const int bk = blockIdx.x, bj = blockIdx.y, bi = blockIdx.z;
    const int i0 = bi * BI, j0 = bj * BJ, k0 = bk * BK;
    const int xg0 = i0 - HL, yg0 = j0 - HL, zg0 = k0 - HL;

    {
        const float4 z4 = make_float4(0.f, 0.f, 0.f, 0.f);
        float4* b4 = reinterpret_cast<float4*>(bins);
        for (int c = t; c < TBINS * 2 / 4; c += 512) b4[c] = z4;
    }
    __syncthreads();

    scatter_phase(src, flow, out, bins, t, i0, j0, k0, xg0, yg0, zg0);
    __syncthreads();

    for (int c = t; c < TCELLS; c += 512) {
        const int z    = c % TK;
        const int rest = c / TK;
        const int b    = rest % TJ;
        const int a    = rest / TJ;

        const int rb = (a * TJS + b) * TKS;
        const int rm = rb - TKS;
        const bool hb = (b < TJS), hm = (b > 0);
        const bool hz = (z < TKS), hzm = (z > 0);

        const u64 Tb  = (hb && hz)  ? bins[rb + z]     : 0ull;
        const u64 Tm  = (hm && hz)  ? bins[rm + z]     : 0ull;
        const u64 Tbz = (hb && hzm) ? bins[rb + z - 1] : 0ull;
        const u64 Tmz = (hm && hzm) ? bins[rm + z - 1] : 0ull;

        if ((Tb | Tm | Tbz | Tmz) == 0ull) continue;

        const int vi = fld0(Tb) + fld1(Tm) + fld2(Tbz) + fld3(Tmz);
        if (vi != 0) {
            const int x = xg0 + a, y = yg0 + b, zz = zg0 + z;
            if (((unsigned)x < (unsigned)H) & ((unsigned)y < (unsigned)W) &
                ((unsigned)zz < (unsigned)Dd)) {
                unsafeAtomicAdd(out + x * WD + y * Dd + zz, (float)vi * (1.0f / 512.0f));
            }
        }
    }
}

extern "C" void kernel_launch(void* const* d_in, const int* in_sizes, int n_in,
                              void* d_out, int out_size, void* d_ws, size_t ws_size,
                              hipStream_t stream) {
    const float* src  = (const float*)d_in[0];
    const float* flow = (const float*)d_in[1];
    float* out = (float*)d_out;

    // out must start zeroed (outlier atomics accumulate on it before B reads it;
    // harness doesn't re-poison between replays).
    (void)hipMemsetAsync(out, 0, (size_t)N * sizeof(float), stream);

    const dim3 block(512);
    const dim3 grid(NBK, NBJ, NBI);  // (6, 24, 24) = 3456 blocks

    if (ws_size >= WS_NEEDED) {
        short* ws = (short*)d_ws;
        splat_tile_kernel<<<grid, block, 0, stream>>>(src, flow, out, ws);
        gather_tiles_kernel<<<(N / 4 + 255) / 256, 256, 0, stream>>>(ws, out);
    } else {
        splat_atomic_kernel<<<grid, block, 0, stream>>>(src, flow, out);
    }
}